// Round 1
// baseline (12999.002 us; speedup 1.0000x reference)
//
#include <hip/hip_runtime.h>
#include <hip/hip_bf16.h>
#include <math.h>

#define BDIM 4
#define TDIM 2048
#define CDIM 2048
#define HDIM 16
#define DDIM 128
#define MROWS (BDIM*TDIM)     /* 8192 */
#define NQKV (3*CDIM)         /* 6144 */
#define KD   CDIM             /* 2048 */
#define HEADSZ (MROWS*CDIM)   /* 16777216 floats = 64MB per Q/K/V buffer */

// NT SGEMM: C[m,n] = sum_k A[m,k] * Bw[n,k]
// MODE 0: scatter output into Q/K/V [B,H,T,D] buffers at out + sel*HEADSZ
// MODE 1: plain row-major out[m*Nsz + n]
template<int MODE>
__global__ __launch_bounds__(256) void sgemm_nt(const float* __restrict__ A,
                                                const float* __restrict__ Bw,
                                                float* __restrict__ out,
                                                int Nsz, int Ksz)
{
    __shared__ float As[16][128];
    __shared__ float Bs[16][128];
    const int tid = threadIdx.x;
    const int m0 = blockIdx.x * 128;
    const int n0 = blockIdx.y * 128;
    const int tx = tid & 15;        // n direction
    const int ty = tid >> 4;        // m direction
    const int lrow = tid >> 2;      // 0..63
    const int lk   = (tid & 3) * 4; // 0,4,8,12

    float acc[8][8];
#pragma unroll
    for (int i = 0; i < 8; ++i)
#pragma unroll
        for (int j = 0; j < 8; ++j) acc[i][j] = 0.f;

    for (int k0 = 0; k0 < Ksz; k0 += 16) {
        // fetch next tiles to registers (overlaps with previous compute)
        const float4 a0 = *(const float4*)&A [(m0 +      lrow) * Ksz + k0 + lk];
        const float4 a1 = *(const float4*)&A [(m0 + 64 + lrow) * Ksz + k0 + lk];
        const float4 b0 = *(const float4*)&Bw[(n0 +      lrow) * Ksz + k0 + lk];
        const float4 b1 = *(const float4*)&Bw[(n0 + 64 + lrow) * Ksz + k0 + lk];
        __syncthreads();   // previous iteration done reading LDS
        As[lk+0][lrow]    = a0.x; As[lk+1][lrow]    = a0.y; As[lk+2][lrow]    = a0.z; As[lk+3][lrow]    = a0.w;
        As[lk+0][64+lrow] = a1.x; As[lk+1][64+lrow] = a1.y; As[lk+2][64+lrow] = a1.z; As[lk+3][64+lrow] = a1.w;
        Bs[lk+0][lrow]    = b0.x; Bs[lk+1][lrow]    = b0.y; Bs[lk+2][lrow]    = b0.z; Bs[lk+3][lrow]    = b0.w;
        Bs[lk+0][64+lrow] = b1.x; Bs[lk+1][64+lrow] = b1.y; Bs[lk+2][64+lrow] = b1.z; Bs[lk+3][64+lrow] = b1.w;
        __syncthreads();
#pragma unroll
        for (int kk = 0; kk < 16; ++kk) {
            float a[8], b[8];
            *(float4*)&a[0] = *(const float4*)&As[kk][ty*8];
            *(float4*)&a[4] = *(const float4*)&As[kk][ty*8+4];
            *(float4*)&b[0] = *(const float4*)&Bs[kk][tx*8];
            *(float4*)&b[4] = *(const float4*)&Bs[kk][tx*8+4];
#pragma unroll
            for (int i = 0; i < 8; ++i)
#pragma unroll
                for (int j = 0; j < 8; ++j)
                    acc[i][j] = fmaf(a[i], b[j], acc[i][j]);
        }
    }

    if (MODE == 0) {
        // scatter into Q/K/V [B,H,T,D]
#pragma unroll
        for (int i = 0; i < 8; ++i) {
            const int m  = m0 + ty*8 + i;
            const int bb = m >> 11;        // /T
            const int tt = m & 2047;
#pragma unroll
            for (int j = 0; j < 8; ++j) {
                const int n   = n0 + tx*8 + j;
                const int sel = n >> 11;   // 0=Q 1=K 2=V
                const int c   = n & 2047;
                const int hh  = c >> 7;
                const int dd  = c & 127;
                out[sel*HEADSZ + ((bb*HDIM + hh)*TDIM + tt)*DDIM + dd] = acc[i][j];
            }
        }
    } else {
#pragma unroll
        for (int i = 0; i < 8; ++i) {
            const int m = m0 + ty*8 + i;
            float4 v0 = make_float4(acc[i][0], acc[i][1], acc[i][2], acc[i][3]);
            float4 v1 = make_float4(acc[i][4], acc[i][5], acc[i][6], acc[i][7]);
            *(float4*)&out[m*Nsz + n0 + tx*8]     = v0;
            *(float4*)&out[m*Nsz + n0 + tx*8 + 4] = v1;
        }
    }
}

// one wave per query row, online softmax, causal
__global__ __launch_bounds__(256) void attn_rows(const float* __restrict__ Q,
                                                 const float* __restrict__ Kb,
                                                 const float* __restrict__ Vb,
                                                 float* __restrict__ att)
{
    const int wave = threadIdx.x >> 6;
    const int lane = threadIdx.x & 63;
    const int r  = blockIdx.x * 4 + wave;   // 0 .. B*H*T-1
    const int bh = r >> 11;                 // head index b*H+h
    const int t  = r & 2047;
    const int b  = bh >> 4;
    const int h  = bh & 15;

    const float* qrow  = Q  + (bh*TDIM + t)*DDIM;
    const float* kbase = Kb + bh*TDIM*DDIM;
    const float* vbase = Vb + bh*TDIM*DDIM;
    const float q0 = qrow[lane];
    const float q1 = qrow[lane + 64];
    const float scale = 0.08838834764831845f;   // 1/sqrt(128)

    float mmax = -INFINITY, l = 0.f, acc0 = 0.f, acc1 = 0.f;
    for (int j = 0; j <= t; ++j) {
        const float* krow = kbase + j*DDIM;
        float s = q0*krow[lane] + q1*krow[lane+64];
        s += __shfl_xor(s, 32);
        s += __shfl_xor(s, 16);
        s += __shfl_xor(s, 8);
        s += __shfl_xor(s, 4);
        s += __shfl_xor(s, 2);
        s += __shfl_xor(s, 1);
        s *= scale;
        const float mnew = fmaxf(mmax, s);
        const float corr = __expf(mmax - mnew);   // 0 on first iter (mmax=-inf)
        const float p    = __expf(s - mnew);
        const float* vrow = vbase + j*DDIM;
        acc0 = acc0*corr + p*vrow[lane];
        acc1 = acc1*corr + p*vrow[lane+64];
        l    = l*corr + p;
        mmax = mnew;
    }
    const float inv = 1.f / l;
    // [B,T,H*D] layout == reference transpose+reshape
    att[(b*TDIM + t)*CDIM + h*DDIM + lane]      = acc0*inv;
    att[(b*TDIM + t)*CDIM + h*DDIM + lane + 64] = acc1*inv;
}

extern "C" void kernel_launch(void* const* d_in, const int* in_sizes, int n_in,
                              void* d_out, int out_size, void* d_ws, size_t ws_size,
                              hipStream_t stream)
{
    const float* x    = (const float*)d_in[0];   // [B,T,C]
    const float* Wqkv = (const float*)d_in[1];   // [3C,C]
    const float* Wout = (const float*)d_in[2];   // [C,C]
    float* out = (float*)d_out;
    float* ws  = (float*)d_ws;

    float* Qb  = ws;                 // [B,H,T,D] 64MB
    float* Kb  = ws + HEADSZ;        // 64MB
    float* Vb  = ws + 2*HEADSZ;      // 64MB
    float* att = out;                // stage attention output [B,T,C] in d_out
    float* fin = ws;                 // final result reuses dead Q region

    dim3 blk(256);
    // 1) QKV projection, scatter to [B,H,T,D]
    sgemm_nt<0><<<dim3(MROWS/128, NQKV/128), blk, 0, stream>>>(x, Wqkv, ws, NQKV, KD);
    // 2) causal attention, one wave per query row
    attn_rows<<<dim3(BDIM*HDIM*TDIM/4), blk, 0, stream>>>(Qb, Kb, Vb, att);
    // 3) output projection (reads att from d_out, writes ws)
    sgemm_nt<1><<<dim3(MROWS/128, CDIM/128), blk, 0, stream>>>(att, Wout, fin, CDIM, KD);
    // 4) move final result into d_out
    hipMemcpyAsync(d_out, fin, (size_t)MROWS*CDIM*sizeof(float),
                   hipMemcpyDeviceToDevice, stream);
}

// Round 3
// 3662.872 us; speedup vs baseline: 3.5489x; 3.5489x over previous
//
#include <hip/hip_runtime.h>
#include <hip/hip_bf16.h>
#include <math.h>

#define BDIM 4
#define TDIM 2048
#define CDIM 2048
#define HDIM 16
#define DDIM 128
#define MROWS (BDIM*TDIM)     /* 8192 */
#define NQKV (3*CDIM)         /* 6144 */
#define KD   CDIM             /* 2048 */
#define QSZ  (MROWS*CDIM)     /* elements per Q/K/V tensor */

typedef __attribute__((ext_vector_type(8))) short short8;
typedef __attribute__((ext_vector_type(4))) unsigned short ushort4v;
typedef __attribute__((ext_vector_type(4))) float f32x4;

__device__ __forceinline__ unsigned short f2bf(float f) {
    unsigned int u = __float_as_uint(f);
    u += 0x7fffu + ((u >> 16) & 1u);        // RNE
    return (unsigned short)(u >> 16);
}

// NT SGEMM: C[m,n] = sum_k A[m,k] * Bw[n,k]
// MODE 0: scatter to Q (fp32 [bh,t,d]) and K/V (bf16 [bh,t,d])
// MODE 1: plain row-major out[m*Nsz + n] fp32
template<int MODE>
__global__ __launch_bounds__(256) void sgemm_nt(const float* __restrict__ A,
                                                const float* __restrict__ Bw,
                                                float* __restrict__ out,
                                                float* __restrict__ qb,
                                                unsigned short* __restrict__ kb,
                                                unsigned short* __restrict__ vb,
                                                int Nsz, int Ksz)
{
    __shared__ float As[16][128];
    __shared__ float Bs[16][128];
    const int tid = threadIdx.x;
    const int m0 = blockIdx.x * 128;
    const int n0 = blockIdx.y * 128;
    const int tx = tid & 15;        // n direction
    const int ty = tid >> 4;        // m direction
    const int lrow = tid >> 2;      // 0..63
    const int lk   = (tid & 3) * 4; // 0,4,8,12

    float acc[8][8];
#pragma unroll
    for (int i = 0; i < 8; ++i)
#pragma unroll
        for (int j = 0; j < 8; ++j) acc[i][j] = 0.f;

    for (int k0 = 0; k0 < Ksz; k0 += 16) {
        const float4 a0 = *(const float4*)&A [(size_t)(m0 +      lrow) * Ksz + k0 + lk];
        const float4 a1 = *(const float4*)&A [(size_t)(m0 + 64 + lrow) * Ksz + k0 + lk];
        const float4 b0 = *(const float4*)&Bw[(size_t)(n0 +      lrow) * Ksz + k0 + lk];
        const float4 b1 = *(const float4*)&Bw[(size_t)(n0 + 64 + lrow) * Ksz + k0 + lk];
        __syncthreads();
        As[lk+0][lrow]    = a0.x; As[lk+1][lrow]    = a0.y; As[lk+2][lrow]    = a0.z; As[lk+3][lrow]    = a0.w;
        As[lk+0][64+lrow] = a1.x; As[lk+1][64+lrow] = a1.y; As[lk+2][64+lrow] = a1.z; As[lk+3][64+lrow] = a1.w;
        Bs[lk+0][lrow]    = b0.x; Bs[lk+1][lrow]    = b0.y; Bs[lk+2][lrow]    = b0.z; Bs[lk+3][lrow]    = b0.w;
        Bs[lk+0][64+lrow] = b1.x; Bs[lk+1][64+lrow] = b1.y; Bs[lk+2][64+lrow] = b1.z; Bs[lk+3][64+lrow] = b1.w;
        __syncthreads();
#pragma unroll
        for (int kk = 0; kk < 16; ++kk) {
            float a[8], b[8];
            *(float4*)&a[0] = *(const float4*)&As[kk][ty*8];
            *(float4*)&a[4] = *(const float4*)&As[kk][ty*8+4];
            *(float4*)&b[0] = *(const float4*)&Bs[kk][tx*8];
            *(float4*)&b[4] = *(const float4*)&Bs[kk][tx*8+4];
#pragma unroll
            for (int i = 0; i < 8; ++i)
#pragma unroll
                for (int j = 0; j < 8; ++j)
                    acc[i][j] = fmaf(a[i], b[j], acc[i][j]);
        }
    }

    if (MODE == 0) {
#pragma unroll
        for (int i = 0; i < 8; ++i) {
            const int m  = m0 + ty*8 + i;
            const int bb = m >> 11;
            const int tt = m & 2047;
#pragma unroll
            for (int j = 0; j < 8; ++j) {
                const int n   = n0 + tx*8 + j;
                const int sel = n >> 11;   // 0=Q 1=K 2=V (uniform per block)
                const int c   = n & 2047;
                const int hh  = c >> 7;
                const int dd  = c & 127;
                const size_t idx = ((size_t)(bb*HDIM + hh)*TDIM + tt)*DDIM + dd;
                if (sel == 0)      qb[idx] = acc[i][j];
                else if (sel == 1) kb[idx] = f2bf(acc[i][j]);
                else               vb[idx] = f2bf(acc[i][j]);
            }
        }
    } else {
#pragma unroll
        for (int i = 0; i < 8; ++i) {
            const int m = m0 + ty*8 + i;
            float4 v0 = make_float4(acc[i][0], acc[i][1], acc[i][2], acc[i][3]);
            float4 v1 = make_float4(acc[i][4], acc[i][5], acc[i][6], acc[i][7]);
            *(float4*)&out[(size_t)m*Nsz + n0 + tx*8]     = v0;
            *(float4*)&out[(size_t)m*Nsz + n0 + tx*8 + 4] = v1;
        }
    }
}

// Flash attention: 4 waves/block, 64 q-rows per block (16/wave), K-tile 64.
// mfma_f32_16x16x32_bf16; C/D layout col=lane&15, row=(lane>>4)*4+reg.
__global__ __launch_bounds__(256) void attn_mfma(const float* __restrict__ Qg,
                                                 const unsigned short* __restrict__ Kg,
                                                 const unsigned short* __restrict__ Vg,
                                                 float* __restrict__ att)
{
    __shared__ unsigned short Ks[64*128];   // [k][d] bf16, swizzled
    __shared__ unsigned short Vs[128*64];   // [d][k] bf16 (transposed), swizzled
    __shared__ unsigned short Ps[4*16*64];  // per-wave P [q][k] bf16, swizzled

    const int tid  = threadIdx.x;
    const int w    = tid >> 6;
    const int lane = tid & 63;
    const int g    = lane >> 4;   // 0..3
    const int c    = lane & 15;   // 0..15
    const int bh   = blockIdx.x & 63;
    const int qt   = 31 - (blockIdx.x >> 6);   // heavy (diagonal-rich) blocks first
    const int q0   = qt * 64;

    // Q fragments, pre-scaled by 1/sqrt(D): A-frag row=c, k(d)=s*32+g*8+j
    short8 qf[4];
    {
        const float* qrow = Qg + ((size_t)bh*TDIM + q0 + w*16 + c) * DDIM + g*8;
        const float sc = 0.08838834764831845f;
#pragma unroll
        for (int s = 0; s < 4; ++s) {
            float4 f0 = *(const float4*)(qrow + s*32);
            float4 f1 = *(const float4*)(qrow + s*32 + 4);
            short8 v;
            v[0]=(short)f2bf(f0.x*sc); v[1]=(short)f2bf(f0.y*sc);
            v[2]=(short)f2bf(f0.z*sc); v[3]=(short)f2bf(f0.w*sc);
            v[4]=(short)f2bf(f1.x*sc); v[5]=(short)f2bf(f1.y*sc);
            v[6]=(short)f2bf(f1.z*sc); v[7]=(short)f2bf(f1.w*sc);
            qf[s] = v;
        }
    }

    f32x4 oacc[8];
#pragma unroll
    for (int i = 0; i < 8; ++i) oacc[i] = (f32x4)(0.f);
    float m_r[4], l_r[4];
#pragma unroll
    for (int r = 0; r < 4; ++r) { m_r[r] = -INFINITY; l_r[r] = 0.f; }

    const unsigned short* Kbh = Kg + (size_t)bh*TDIM*DDIM;
    const unsigned short* Vbh = Vg + (size_t)bh*TDIM*DDIM;

    for (int kt = 0; kt <= qt; ++kt) {
        __syncthreads();   // previous iteration done reading Ks/Vs
        // stage K rows (swizzled) and V transposed (swizzled), bf16
#pragma unroll
        for (int p = 0; p < 8; ++p) {
            const int idx = p*256 + tid;          // 0..2047
            const int kr  = idx >> 5;             // 0..63 (t within tile)
            const int dj  = (idx & 31) * 4;       // 0..124
            ushort4v kv = *(const ushort4v*)(Kbh + ((size_t)(kt*64 + kr))*DDIM + dj);
            *(ushort4v*)&Ks[(kr*128 + dj) ^ ((kr&7)<<3)] = kv;
            ushort4v vv = *(const ushort4v*)(Vbh + ((size_t)(kt*64 + kr))*DDIM + dj);
#pragma unroll
            for (int e = 0; e < 4; ++e) {
                const int d = dj + e;
                Vs[(d*64 + kr) ^ ((d&7)<<3)] = vv[e];
            }
        }
        __syncthreads();

        // S = Q K^T  (16q x 64k per wave)
        f32x4 sa[4];
#pragma unroll
        for (int n = 0; n < 4; ++n) sa[n] = (f32x4)(0.f);
#pragma unroll
        for (int s = 0; s < 4; ++s) {
#pragma unroll
            for (int n = 0; n < 4; ++n) {
                const int row = n*16 + c;   // B-frag col = k row of Ks
                short8 bf = *(const short8*)&Ks[(row*128 + s*32 + g*8) ^ ((row&7)<<3)];
                sa[n] = __builtin_amdgcn_mfma_f32_16x16x32_bf16(qf[s], bf, sa[n], 0, 0, 0);
            }
        }

        if (kt == qt) {   // diagonal tile: causal mask (local compare valid since q0==kt*64)
#pragma unroll
            for (int n = 0; n < 4; ++n) {
                const int k = n*16 + c;
#pragma unroll
                for (int r = 0; r < 4; ++r) {
                    const int q = w*16 + g*4 + r;
                    if (k > q) sa[n][r] = -INFINITY;
                }
            }
        }

        // online softmax (rows live in 16-lane groups; shfl widths 1/2/4/8)
        float corr[4];
#pragma unroll
        for (int r = 0; r < 4; ++r) {
            float mx = fmaxf(fmaxf(sa[0][r], sa[1][r]), fmaxf(sa[2][r], sa[3][r]));
            mx = fmaxf(mx, __shfl_xor(mx, 1));
            mx = fmaxf(mx, __shfl_xor(mx, 2));
            mx = fmaxf(mx, __shfl_xor(mx, 4));
            mx = fmaxf(mx, __shfl_xor(mx, 8));
            const float mn = fmaxf(m_r[r], mx);
            corr[r] = __expf(m_r[r] - mn);
            float rs = 0.f;
#pragma unroll
            for (int n = 0; n < 4; ++n) {
                const float p = __expf(sa[n][r] - mn);
                sa[n][r] = p;
                rs += p;
            }
            rs += __shfl_xor(rs, 1);
            rs += __shfl_xor(rs, 2);
            rs += __shfl_xor(rs, 4);
            rs += __shfl_xor(rs, 8);
            l_r[r] = l_r[r]*corr[r] + rs;
            m_r[r] = mn;
        }
#pragma unroll
        for (int i = 0; i < 8; ++i) {
            f32x4 o = oacc[i];
            o[0] *= corr[0]; o[1] *= corr[1]; o[2] *= corr[2]; o[3] *= corr[3];
            oacc[i] = o;
        }

        // P: C-layout -> LDS (per-wave, swizzled) -> A-frag layout
        unsigned short* Pw = &Ps[w*1024];
#pragma unroll
        for (int n = 0; n < 4; ++n)
#pragma unroll
            for (int r = 0; r < 4; ++r) {
                const int q = g*4 + r, k = n*16 + c;
                Pw[(q*64 + k) ^ ((q&7)<<3)] = f2bf(sa[n][r]);
            }
        short8 pf[2];
#pragma unroll
        for (int s2 = 0; s2 < 2; ++s2)
            pf[s2] = *(const short8*)&Pw[(c*64 + s2*32 + g*8) ^ ((c&7)<<3)];

        // O += P V   (16q x 128d per wave)
#pragma unroll
        for (int s2 = 0; s2 < 2; ++s2)
#pragma unroll
            for (int dt = 0; dt < 8; ++dt) {
                const int d = dt*16 + c;   // B-frag col = d row of Vs
                short8 vf = *(const short8*)&Vs[(d*64 + s2*32 + g*8) ^ ((d&7)<<3)];
                oacc[dt] = __builtin_amdgcn_mfma_f32_16x16x32_bf16(pf[s2], vf, oacc[dt], 0, 0, 0);
            }
    }

    // epilogue: normalize, store to att [B,T,H*D]
    float inv[4];
#pragma unroll
    for (int r = 0; r < 4; ++r) inv[r] = 1.f / l_r[r];
    const int b = bh >> 4, h = bh & 15;
    float* obase = att + ((size_t)b*TDIM + q0 + w*16 + g*4)*CDIM + h*DDIM + c;
#pragma unroll
    for (int dt = 0; dt < 8; ++dt)
#pragma unroll
        for (int r = 0; r < 4; ++r)
            obase[(size_t)r*CDIM + dt*16] = oacc[dt][r] * inv[r];
}

extern "C" void kernel_launch(void* const* d_in, const int* in_sizes, int n_in,
                              void* d_out, int out_size, void* d_ws, size_t ws_size,
                              hipStream_t stream)
{
    const float* x    = (const float*)d_in[0];   // [B,T,C]
    const float* Wqkv = (const float*)d_in[1];   // [3C,C]
    const float* Wout = (const float*)d_in[2];   // [C,C]
    float* out = (float*)d_out;
    float* ws  = (float*)d_ws;

    float*          Qb = ws;                               // fp32 [bh,t,d] 64MB
    unsigned short* Kb = (unsigned short*)(ws + QSZ);      // bf16 [bh,t,d] 32MB
    unsigned short* Vb = Kb + QSZ;                         // bf16 [bh,t,d] 32MB
    float* att = out;    // stage attention output [B,T,C] in d_out
    float* fin = ws;     // final result reuses dead Q region

    dim3 blk(256);
    sgemm_nt<0><<<dim3(MROWS/128, NQKV/128), blk, 0, stream>>>(x, Wqkv, nullptr, Qb, Kb, Vb, NQKV, KD);
    attn_mfma<<<dim3(64*32), blk, 0, stream>>>(Qb, Kb, Vb, att);
    sgemm_nt<1><<<dim3(MROWS/128, CDIM/128), blk, 0, stream>>>(att, Wout, fin, nullptr, nullptr, nullptr, CDIM, KD);
    hipMemcpyAsync(d_out, fin, (size_t)MROWS*CDIM*sizeof(float),
                   hipMemcpyDeviceToDevice, stream);
}

// Round 4
// 845.773 us; speedup vs baseline: 15.3694x; 4.3308x over previous
//
#include <hip/hip_runtime.h>
#include <hip/hip_bf16.h>
#include <math.h>

#define BDIM 4
#define TDIM 2048
#define CDIM 2048
#define HDIM 16
#define DDIM 128
#define MROWS (BDIM*TDIM)     /* 8192 */
#define NQKV (3*CDIM)         /* 6144 */
#define GK   CDIM             /* 2048 = K of both GEMMs */
#define QSZ  (MROWS*CDIM)     /* elements per Q/K/V tensor */

typedef __attribute__((ext_vector_type(8))) short short8;
typedef __attribute__((ext_vector_type(4))) unsigned short ushort4v;
typedef __attribute__((ext_vector_type(4))) float f32x4;

__device__ __forceinline__ unsigned short f2bf(float f) {
    unsigned int u = __float_as_uint(f);
    u += 0x7fffu + ((u >> 16) & 1u);        // RNE
    return (unsigned short)(u >> 16);
}

__device__ __forceinline__ void gload16(const unsigned short* g, unsigned short* l) {
    // direct global->LDS DMA, 16B per lane; LDS dest = uniform base + lane*16
    __builtin_amdgcn_global_load_lds((__attribute__((address_space(1))) void*)(g),
                                     (__attribute__((address_space(3))) void*)(l),
                                     16, 0, 0);
}

// fp32 -> bf16 bulk convert (memory-bound)
__global__ __launch_bounds__(256) void cvt_bf16(const float* __restrict__ in,
                                                unsigned short* __restrict__ outp,
                                                int n4)
{
    const int stride = gridDim.x * blockDim.x;
    for (int i = blockIdx.x * blockDim.x + threadIdx.x; i < n4; i += stride) {
        float4 f = ((const float4*)in)[i];
        ushort4v u;
        u[0] = f2bf(f.x); u[1] = f2bf(f.y); u[2] = f2bf(f.z); u[3] = f2bf(f.w);
        ((ushort4v*)outp)[i] = u;
    }
}

// bf16 NT GEMM (m97 structure): C[m,n] = sum_k A[m,k]*B[n,k], fp32 accum.
// 128x128 tile, 4 waves (2x2 of 64x64), BK=32, global_load_lds staging.
// MODE 0: scatter bf16 to Q/K/V [bh,t,d].  MODE 1: fp32 row-major outp.
template<int MODE>
__global__ __launch_bounds__(256) void gemm_bt(const unsigned short* __restrict__ A,
                                               const unsigned short* __restrict__ B,
                                               float* __restrict__ outp,
                                               unsigned short* __restrict__ qb,
                                               unsigned short* __restrict__ kb,
                                               unsigned short* __restrict__ vb,
                                               int Nsz)
{
    __shared__ __align__(16) unsigned short As[128*32];   // [row][k] 64B/row
    __shared__ __align__(16) unsigned short Bs[128*32];
    const int tid  = threadIdx.x;
    const int w    = tid >> 6;
    const int lane = tid & 63;
    const int wr   = w >> 1, wc = w & 1;
    const int m0   = blockIdx.x * 128, n0 = blockIdx.y * 128;
    const int fr   = lane & 15;       // frag row (A) / col (B)
    const int fg   = lane >> 4;       // k-group: k = fg*8 + j

    // staging: lane covers row=lane>>2 (of 16), k-chunk (lane&3)*8 elems
    const int srow = lane >> 2, skel = (lane & 3) * 8;
    const unsigned short* Ag0 = A + (size_t)(m0 +      w*16 + srow)*GK + skel;
    const unsigned short* Ag1 = A + (size_t)(m0 + 64 + w*16 + srow)*GK + skel;
    const unsigned short* Bg0 = B + (size_t)(n0 +      w*16 + srow)*GK + skel;
    const unsigned short* Bg1 = B + (size_t)(n0 + 64 + w*16 + srow)*GK + skel;
    unsigned short* Al0 = &As[ w      * 512];
    unsigned short* Al1 = &As[(4 + w) * 512];
    unsigned short* Bl0 = &Bs[ w      * 512];
    unsigned short* Bl1 = &Bs[(4 + w) * 512];

    f32x4 acc[4][4];
#pragma unroll
    for (int i = 0; i < 4; ++i)
#pragma unroll
        for (int j = 0; j < 4; ++j) acc[i][j] = (f32x4)(0.f);

    for (int k0 = 0; k0 < GK; k0 += 32) {
        __syncthreads();                 // prev iter done reading LDS
        gload16(Ag0 + k0, Al0);
        gload16(Ag1 + k0, Al1);
        gload16(Bg0 + k0, Bl0);
        gload16(Bg1 + k0, Bl1);
        __syncthreads();                 // drains vmcnt -> LDS valid

        short8 af[4], bfr[4];
#pragma unroll
        for (int mi = 0; mi < 4; ++mi)
            af[mi] = *(const short8*)&As[(wr*64 + mi*16 + fr)*32 + fg*8];
#pragma unroll
        for (int nj = 0; nj < 4; ++nj)
            bfr[nj] = *(const short8*)&Bs[(wc*64 + nj*16 + fr)*32 + fg*8];
#pragma unroll
        for (int mi = 0; mi < 4; ++mi)
#pragma unroll
            for (int nj = 0; nj < 4; ++nj)
                acc[mi][nj] = __builtin_amdgcn_mfma_f32_16x16x32_bf16(af[mi], bfr[nj], acc[mi][nj], 0, 0, 0);
    }

    // C/D layout: col = lane&15 (=fr), row = fg*4 + r
    if (MODE == 0) {
#pragma unroll
        for (int mi = 0; mi < 4; ++mi)
#pragma unroll
            for (int nj = 0; nj < 4; ++nj) {
                const int n   = n0 + wc*64 + nj*16 + fr;
                const int sel = n >> 11;          // 0=Q 1=K 2=V (block-uniform)
                const int c   = n & 2047;
                const int hh  = c >> 7, dd = c & 127;
#pragma unroll
                for (int r = 0; r < 4; ++r) {
                    const int m  = m0 + wr*64 + mi*16 + fg*4 + r;
                    const int bb = m >> 11, tt = m & 2047;
                    const size_t idx = ((size_t)(bb*HDIM + hh)*TDIM + tt)*DDIM + dd;
                    const unsigned short v = f2bf(acc[mi][nj][r]);
                    if (sel == 0)      qb[idx] = v;
                    else if (sel == 1) kb[idx] = v;
                    else               vb[idx] = v;
                }
            }
    } else {
#pragma unroll
        for (int mi = 0; mi < 4; ++mi)
#pragma unroll
            for (int nj = 0; nj < 4; ++nj) {
                const int n = n0 + wc*64 + nj*16 + fr;
#pragma unroll
                for (int r = 0; r < 4; ++r) {
                    const int m = m0 + wr*64 + mi*16 + fg*4 + r;
                    outp[(size_t)m*Nsz + n] = acc[mi][nj][r];
                }
            }
    }
}

// Flash attention: 4 waves/block, 64 q-rows/block (16/wave), K-tile 64.
// Q/K/V bf16 [bh,t,d]; softmax scale folded into exp; bf16 output [B,T,H*D].
__global__ __launch_bounds__(256) void attn_mfma(const unsigned short* __restrict__ Qg,
                                                 const unsigned short* __restrict__ Kg,
                                                 const unsigned short* __restrict__ Vg,
                                                 unsigned short* __restrict__ attb)
{
    __shared__ unsigned short Ks[64*128];   // [k][d] bf16, swizzled
    __shared__ unsigned short Vs[128*64];   // [d][k] bf16 (transposed), swizzled
    __shared__ unsigned short Ps[4*16*64];  // per-wave P [q][k] bf16, swizzled

    const int tid  = threadIdx.x;
    const int w    = tid >> 6;
    const int lane = tid & 63;
    const int g    = lane >> 4;
    const int c    = lane & 15;
    const int bh   = blockIdx.x & 63;
    const int qt   = 31 - (blockIdx.x >> 6);   // heavy blocks first
    const int q0   = qt * 64;
    const float sc = 0.08838834764831845f;     // 1/sqrt(128)

    short8 qf[4];
    {
        const unsigned short* qrow = Qg + ((size_t)bh*TDIM + q0 + w*16 + c)*DDIM + g*8;
#pragma unroll
        for (int s = 0; s < 4; ++s)
            qf[s] = *(const short8*)(qrow + s*32);
    }

    f32x4 oacc[8];
#pragma unroll
    for (int i = 0; i < 8; ++i) oacc[i] = (f32x4)(0.f);
    float m_r[4], l_r[4];
#pragma unroll
    for (int r = 0; r < 4; ++r) { m_r[r] = -INFINITY; l_r[r] = 0.f; }

    const unsigned short* Kbh = Kg + (size_t)bh*TDIM*DDIM;
    const unsigned short* Vbh = Vg + (size_t)bh*TDIM*DDIM;

    for (int kt = 0; kt <= qt; ++kt) {
        __syncthreads();
#pragma unroll
        for (int p = 0; p < 8; ++p) {
            const int idx = p*256 + tid;
            const int kr  = idx >> 5;
            const int dj  = (idx & 31) * 4;
            ushort4v kv = *(const ushort4v*)(Kbh + ((size_t)(kt*64 + kr))*DDIM + dj);
            *(ushort4v*)&Ks[(kr*128 + dj) ^ ((kr&7)<<3)] = kv;
            ushort4v vv = *(const ushort4v*)(Vbh + ((size_t)(kt*64 + kr))*DDIM + dj);
#pragma unroll
            for (int e = 0; e < 4; ++e) {
                const int d = dj + e;
                Vs[(d*64 + kr) ^ ((d&7)<<3)] = vv[e];
            }
        }
        __syncthreads();

        // S = Q K^T (unscaled)
        f32x4 sa[4];
#pragma unroll
        for (int n = 0; n < 4; ++n) sa[n] = (f32x4)(0.f);
#pragma unroll
        for (int s = 0; s < 4; ++s)
#pragma unroll
            for (int n = 0; n < 4; ++n) {
                const int row = n*16 + c;
                short8 bf = *(const short8*)&Ks[(row*128 + s*32 + g*8) ^ ((row&7)<<3)];
                sa[n] = __builtin_amdgcn_mfma_f32_16x16x32_bf16(qf[s], bf, sa[n], 0, 0, 0);
            }

        if (kt == qt) {
#pragma unroll
            for (int n = 0; n < 4; ++n) {
                const int k = n*16 + c;
#pragma unroll
                for (int r = 0; r < 4; ++r) {
                    const int q = w*16 + g*4 + r;
                    if (k > q) sa[n][r] = -INFINITY;
                }
            }
        }

        float corr[4];
#pragma unroll
        for (int r = 0; r < 4; ++r) {
            float mx = fmaxf(fmaxf(sa[0][r], sa[1][r]), fmaxf(sa[2][r], sa[3][r]));
            mx = fmaxf(mx, __shfl_xor(mx, 1));
            mx = fmaxf(mx, __shfl_xor(mx, 2));
            mx = fmaxf(mx, __shfl_xor(mx, 4));
            mx = fmaxf(mx, __shfl_xor(mx, 8));
            const float mn = fmaxf(m_r[r], mx);
            corr[r] = __expf((m_r[r] - mn) * sc);
            float rs = 0.f;
#pragma unroll
            for (int n = 0; n < 4; ++n) {
                const float p = __expf((sa[n][r] - mn) * sc);
                sa[n][r] = p;
                rs += p;
            }
            rs += __shfl_xor(rs, 1);
            rs += __shfl_xor(rs, 2);
            rs += __shfl_xor(rs, 4);
            rs += __shfl_xor(rs, 8);
            l_r[r] = l_r[r]*corr[r] + rs;
            m_r[r] = mn;
        }
#pragma unroll
        for (int i = 0; i < 8; ++i) {
            f32x4 o = oacc[i];
            o[0] *= corr[0]; o[1] *= corr[1]; o[2] *= corr[2]; o[3] *= corr[3];
            oacc[i] = o;
        }

        unsigned short* Pw = &Ps[w*1024];
#pragma unroll
        for (int n = 0; n < 4; ++n)
#pragma unroll
            for (int r = 0; r < 4; ++r) {
                const int q = g*4 + r, k = n*16 + c;
                Pw[(q*64 + k) ^ ((q&7)<<3)] = f2bf(sa[n][r]);
            }
        short8 pf[2];
#pragma unroll
        for (int s2 = 0; s2 < 2; ++s2)
            pf[s2] = *(const short8*)&Pw[(c*64 + s2*32 + g*8) ^ ((c&7)<<3)];

#pragma unroll
        for (int s2 = 0; s2 < 2; ++s2)
#pragma unroll
            for (int dt = 0; dt < 8; ++dt) {
                const int d = dt*16 + c;
                short8 vf = *(const short8*)&Vs[(d*64 + s2*32 + g*8) ^ ((d&7)<<3)];
                oacc[dt] = __builtin_amdgcn_mfma_f32_16x16x32_bf16(pf[s2], vf, oacc[dt], 0, 0, 0);
            }
    }

    float inv[4];
#pragma unroll
    for (int r = 0; r < 4; ++r) inv[r] = 1.f / l_r[r];
    const int b = bh >> 4, h = bh & 15;
    unsigned short* obase = attb + ((size_t)b*TDIM + q0 + w*16 + g*4)*CDIM + h*DDIM + c;
#pragma unroll
    for (int dt = 0; dt < 8; ++dt)
#pragma unroll
        for (int r = 0; r < 4; ++r)
            obase[(size_t)r*CDIM + dt*16] = f2bf(oacc[dt][r] * inv[r]);
}

extern "C" void kernel_launch(void* const* d_in, const int* in_sizes, int n_in,
                              void* d_out, int out_size, void* d_ws, size_t ws_size,
                              hipStream_t stream)
{
    const float* x    = (const float*)d_in[0];   // [B,T,C]
    const float* Wqkv = (const float*)d_in[1];   // [3C,C]
    const float* Wout = (const float*)d_in[2];   // [C,C]
    float* out = (float*)d_out;

    unsigned short* ws = (unsigned short*)d_ws;
    unsigned short* xb    = ws;                       // [8192][2048]  32MB
    unsigned short* Wqkvb = xb    + (size_t)MROWS*CDIM;   // [6144][2048] 24MB
    unsigned short* Woutb = Wqkvb + (size_t)NQKV*CDIM;    // [2048][2048]  8MB
    unsigned short* Qb    = Woutb + (size_t)CDIM*CDIM;    // [bh,t,d] 32MB
    unsigned short* Kb    = Qb + QSZ;
    unsigned short* Vb    = Kb + QSZ;
    unsigned short* attb  = Vb + QSZ;                     // [8192][2048] 32MB

    dim3 blk(256);
    cvt_bf16<<<2048, blk, 0, stream>>>(x,    xb,    MROWS*CDIM/4);
    cvt_bf16<<<2048, blk, 0, stream>>>(Wqkv, Wqkvb, NQKV*CDIM/4);
    cvt_bf16<<<1024, blk, 0, stream>>>(Wout, Woutb, CDIM*CDIM/4);
    gemm_bt<0><<<dim3(MROWS/128, NQKV/128), blk, 0, stream>>>(xb, Wqkvb, nullptr, Qb, Kb, Vb, NQKV);
    attn_mfma<<<dim3(64*32), blk, 0, stream>>>(Qb, Kb, Vb, attb);
    gemm_bt<1><<<dim3(MROWS/128, CDIM/128), blk, 0, stream>>>(attb, Woutb, out, nullptr, nullptr, nullptr, CDIM);
}

// Round 5
// 564.624 us; speedup vs baseline: 23.0224x; 1.4979x over previous
//
#include <hip/hip_runtime.h>
#include <hip/hip_bf16.h>
#include <math.h>

#define BDIM 4
#define TDIM 2048
#define CDIM 2048
#define HDIM 16
#define DDIM 128
#define MROWS (BDIM*TDIM)     /* 8192 */
#define NQKV (3*CDIM)         /* 6144 */
#define GK   CDIM             /* 2048 = K of both GEMMs */
#define QSZ  (MROWS*CDIM)     /* elements per Q/K/V tensor */

typedef __attribute__((ext_vector_type(8))) short short8;
typedef __attribute__((ext_vector_type(4))) unsigned short ushort4v;
typedef __attribute__((ext_vector_type(4))) float f32x4;

__device__ __forceinline__ unsigned short f2bf(float f) {
    unsigned int u = __float_as_uint(f);
    u += 0x7fffu + ((u >> 16) & 1u);        // RNE
    return (unsigned short)(u >> 16);
}

__device__ __forceinline__ void gload16(const unsigned short* g, unsigned short* l) {
    // direct global->LDS DMA, 16B/lane; LDS dest = wave-uniform base + lane*16
    __builtin_amdgcn_global_load_lds((__attribute__((address_space(1))) void*)(g),
                                     (__attribute__((address_space(3))) void*)(l),
                                     16, 0, 0);
}

// fp32 -> bf16 bulk convert (memory-bound)
__global__ __launch_bounds__(256) void cvt_bf16(const float* __restrict__ in,
                                                unsigned short* __restrict__ outp,
                                                int n4)
{
    const int stride = gridDim.x * blockDim.x;
    for (int i = blockIdx.x * blockDim.x + threadIdx.x; i < n4; i += stride) {
        float4 f = ((const float4*)in)[i];
        ushort4v u;
        u[0] = f2bf(f.x); u[1] = f2bf(f.y); u[2] = f2bf(f.z); u[3] = f2bf(f.w);
        ((ushort4v*)outp)[i] = u;
    }
}

// bf16 NT GEMM (m97 structure): C[m,n] = sum_k A[m,k]*B[n,k], fp32 accum.
// MODE 0: scatter bf16 to Q/K [bh,t,d] and V TRANSPOSED [bh,d,t].
// MODE 1: fp32 row-major outp.
template<int MODE>
__global__ __launch_bounds__(256) void gemm_bt(const unsigned short* __restrict__ A,
                                               const unsigned short* __restrict__ B,
                                               float* __restrict__ outp,
                                               unsigned short* __restrict__ qb,
                                               unsigned short* __restrict__ kb,
                                               unsigned short* __restrict__ vt,
                                               int Nsz)
{
    __shared__ __align__(16) unsigned short As[128*32];
    __shared__ __align__(16) unsigned short Bs[128*32];
    const int tid  = threadIdx.x;
    const int w    = tid >> 6;
    const int lane = tid & 63;
    const int wr   = w >> 1, wc = w & 1;
    const int m0   = blockIdx.x * 128, n0 = blockIdx.y * 128;
    const int fr   = lane & 15;
    const int fg   = lane >> 4;

    const int srow = lane >> 2, skel = (lane & 3) * 8;
    const unsigned short* Ag0 = A + (size_t)(m0 +      w*16 + srow)*GK + skel;
    const unsigned short* Ag1 = A + (size_t)(m0 + 64 + w*16 + srow)*GK + skel;
    const unsigned short* Bg0 = B + (size_t)(n0 +      w*16 + srow)*GK + skel;
    const unsigned short* Bg1 = B + (size_t)(n0 + 64 + w*16 + srow)*GK + skel;
    unsigned short* Al0 = &As[ w      * 512];
    unsigned short* Al1 = &As[(4 + w) * 512];
    unsigned short* Bl0 = &Bs[ w      * 512];
    unsigned short* Bl1 = &Bs[(4 + w) * 512];

    f32x4 acc[4][4];
#pragma unroll
    for (int i = 0; i < 4; ++i)
#pragma unroll
        for (int j = 0; j < 4; ++j) acc[i][j] = (f32x4)(0.f);

    for (int k0 = 0; k0 < GK; k0 += 32) {
        __syncthreads();
        gload16(Ag0 + k0, Al0);
        gload16(Ag1 + k0, Al1);
        gload16(Bg0 + k0, Bl0);
        gload16(Bg1 + k0, Bl1);
        __syncthreads();

        short8 af[4], bfr[4];
#pragma unroll
        for (int mi = 0; mi < 4; ++mi)
            af[mi] = *(const short8*)&As[(wr*64 + mi*16 + fr)*32 + fg*8];
#pragma unroll
        for (int nj = 0; nj < 4; ++nj)
            bfr[nj] = *(const short8*)&Bs[(wc*64 + nj*16 + fr)*32 + fg*8];
#pragma unroll
        for (int mi = 0; mi < 4; ++mi)
#pragma unroll
            for (int nj = 0; nj < 4; ++nj)
                acc[mi][nj] = __builtin_amdgcn_mfma_f32_16x16x32_bf16(af[mi], bfr[nj], acc[mi][nj], 0, 0, 0);
    }

    if (MODE == 0) {
#pragma unroll
        for (int mi = 0; mi < 4; ++mi)
#pragma unroll
            for (int nj = 0; nj < 4; ++nj) {
                const int n   = n0 + wc*64 + nj*16 + fr;
                const int sel = n >> 11;          // 0=Q 1=K 2=V (block-uniform)
                const int c   = n & 2047;
                const int hh  = c >> 7, dd = c & 127;
#pragma unroll
                for (int r = 0; r < 4; ++r) {
                    const int m  = m0 + wr*64 + mi*16 + fg*4 + r;
                    const int bb = m >> 11, tt = m & 2047;
                    const unsigned short v = f2bf(acc[mi][nj][r]);
                    if (sel == 0)
                        qb[((size_t)(bb*HDIM + hh)*TDIM + tt)*DDIM + dd] = v;
                    else if (sel == 1)
                        kb[((size_t)(bb*HDIM + hh)*TDIM + tt)*DDIM + dd] = v;
                    else  // V transposed: [bh][d][t]
                        vt[((size_t)(bb*HDIM + hh)*DDIM + dd)*TDIM + tt] = v;
                }
            }
    } else {
#pragma unroll
        for (int mi = 0; mi < 4; ++mi)
#pragma unroll
            for (int nj = 0; nj < 4; ++nj) {
                const int n = n0 + wc*64 + nj*16 + fr;
#pragma unroll
                for (int r = 0; r < 4; ++r) {
                    const int m = m0 + wr*64 + mi*16 + fg*4 + r;
                    outp[(size_t)m*Nsz + n] = acc[mi][nj][r];
                }
            }
    }
}

// Flash attention: 4 waves, 64 q-rows/block, K-tile 64.
// K [bh][t][d], V^T [bh][d][t] staged via global_load_lds with pre-swizzled
// source (linear LDS dest, XOR-swizzled reads). K double-buffered, V single.
__global__ __launch_bounds__(256) void attn_mfma(const unsigned short* __restrict__ Qg,
                                                 const unsigned short* __restrict__ Kg,
                                                 const unsigned short* __restrict__ Vt,
                                                 unsigned short* __restrict__ attb)
{
    __shared__ __align__(16) unsigned short Ks[2][64*128];  // 2x16KB
    __shared__ __align__(16) unsigned short Vs[128*64];     // 16KB  [d][k]
    __shared__ __align__(16) unsigned short Ps[4*16*64];    // 8KB

    const int tid  = threadIdx.x;
    const int w    = tid >> 6;
    const int lane = tid & 63;
    const int g    = lane >> 4;
    const int c    = lane & 15;
    const int bh   = blockIdx.x & 63;
    const int qt   = 31 - (blockIdx.x >> 6);   // heavy blocks first
    const int q0   = qt * 64;
    const float sc = 0.08838834764831845f;     // 1/sqrt(128)

    const unsigned short* Kbh  = Kg + (size_t)bh*TDIM*DDIM;
    const unsigned short* Vtbh = Vt + (size_t)bh*DDIM*TDIM;

    short8 qf[4];
    {
        const unsigned short* qrow = Qg + ((size_t)bh*TDIM + q0 + w*16 + c)*DDIM + g*8;
#pragma unroll
        for (int s = 0; s < 4; ++s)
            qf[s] = *(const short8*)(qrow + s*32);
    }

    f32x4 oacc[8];
#pragma unroll
    for (int i = 0; i < 8; ++i) oacc[i] = (f32x4)(0.f);
    float m_r[4], l_r[4];
#pragma unroll
    for (int r = 0; r < 4; ++r) { m_r[r] = -INFINITY; l_r[r] = 0.f; }

    // --- staging helpers (pre-swizzled global source, linear LDS dest) ---
    // K tile: wave w -> rows [w*16, w*16+16); call j: row = w*16+j*4+(lane>>4),
    //         16B-unit sub = (lane&15) ^ (row&7)
    // V tile: wave w -> d-rows [w*32, w*32+32); call j: d = w*32+j*8+(lane>>3),
    //         16B-unit sub = (lane&7) ^ (d&7)
#define STAGE_K(buf, kt_)                                                        \
    {                                                                            \
        _Pragma("unroll")                                                        \
        for (int j = 0; j < 4; ++j) {                                            \
            const int rw  = w*16 + j*4 + (lane >> 4);                            \
            const int sub = (lane & 15) ^ (rw & 7);                              \
            gload16(Kbh + ((size_t)((kt_)*64 + rw))*DDIM + sub*8,                \
                    &Ks[buf][w*2048 + j*512]);                                   \
        }                                                                        \
    }
#define STAGE_V(kt_)                                                             \
    {                                                                            \
        _Pragma("unroll")                                                        \
        for (int j = 0; j < 4; ++j) {                                            \
            const int d   = w*32 + j*8 + (lane >> 3);                            \
            const int sub = (lane & 7) ^ (d & 7);                                \
            gload16(Vtbh + (size_t)d*TDIM + (kt_)*64 + sub*8,                    \
                    &Vs[w*2048 + j*512]);                                        \
        }                                                                        \
    }

    STAGE_K(0, 0);
    STAGE_V(0);
    __syncthreads();

    for (int kt = 0; kt <= qt; ++kt) {
        const int cur = kt & 1;
        if (kt < qt) STAGE_K(cur ^ 1, kt + 1);
        if (kt > 0)  STAGE_V(kt);

        // S = Q K^T (unscaled)
        f32x4 sa[4];
#pragma unroll
        for (int n = 0; n < 4; ++n) sa[n] = (f32x4)(0.f);
#pragma unroll
        for (int s = 0; s < 4; ++s)
#pragma unroll
            for (int n = 0; n < 4; ++n) {
                const int row = n*16 + c;
                short8 bf = *(const short8*)&Ks[cur][(row*128 + s*32 + g*8) ^ ((row&7)<<3)];
                sa[n] = __builtin_amdgcn_mfma_f32_16x16x32_bf16(qf[s], bf, sa[n], 0, 0, 0);
            }

        if (kt == qt) {   // causal mask on diagonal tile
#pragma unroll
            for (int n = 0; n < 4; ++n) {
                const int k = n*16 + c;
#pragma unroll
                for (int r = 0; r < 4; ++r) {
                    const int q = w*16 + g*4 + r;
                    if (k > q) sa[n][r] = -INFINITY;
                }
            }
        }

        // online softmax (rows in 16-lane groups)
        float corr[4];
#pragma unroll
        for (int r = 0; r < 4; ++r) {
            float mx = fmaxf(fmaxf(sa[0][r], sa[1][r]), fmaxf(sa[2][r], sa[3][r]));
            mx = fmaxf(mx, __shfl_xor(mx, 1));
            mx = fmaxf(mx, __shfl_xor(mx, 2));
            mx = fmaxf(mx, __shfl_xor(mx, 4));
            mx = fmaxf(mx, __shfl_xor(mx, 8));
            const float mn = fmaxf(m_r[r], mx);
            corr[r] = __expf((m_r[r] - mn) * sc);
            float rs = 0.f;
#pragma unroll
            for (int n = 0; n < 4; ++n) {
                const float p = __expf((sa[n][r] - mn) * sc);
                sa[n][r] = p;
                rs += p;
            }
            rs += __shfl_xor(rs, 1);
            rs += __shfl_xor(rs, 2);
            rs += __shfl_xor(rs, 4);
            rs += __shfl_xor(rs, 8);
            l_r[r] = l_r[r]*corr[r] + rs;
            m_r[r] = mn;
        }
#pragma unroll
        for (int i = 0; i < 8; ++i) {
            f32x4 o = oacc[i];
            o[0] *= corr[0]; o[1] *= corr[1]; o[2] *= corr[2]; o[3] *= corr[3];
            oacc[i] = o;
        }

        // P: C-layout -> per-wave LDS -> A-frag layout
        unsigned short* Pw = &Ps[w*1024];
#pragma unroll
        for (int n = 0; n < 4; ++n)
#pragma unroll
            for (int r = 0; r < 4; ++r) {
                const int q = g*4 + r, k = n*16 + c;
                Pw[(q*64 + k) ^ ((q&7)<<3)] = f2bf(sa[n][r]);
            }
        short8 pf[2];
#pragma unroll
        for (int s2 = 0; s2 < 2; ++s2)
            pf[s2] = *(const short8*)&Pw[(c*64 + s2*32 + g*8) ^ ((c&7)<<3)];

        __syncthreads();   // drains vmcnt: V[kt] (and K[kt+1]) landed

        // O += P V
#pragma unroll
        for (int s2 = 0; s2 < 2; ++s2)
#pragma unroll
            for (int dt = 0; dt < 8; ++dt) {
                const int d = dt*16 + c;
                short8 vf = *(const short8*)&Vs[(d*64 + s2*32 + g*8) ^ ((d&7)<<3)];
                oacc[dt] = __builtin_amdgcn_mfma_f32_16x16x32_bf16(pf[s2], vf, oacc[dt], 0, 0, 0);
            }

        __syncthreads();   // PV readers done before next V-stage overwrites
    }

    float inv[4];
#pragma unroll
    for (int r = 0; r < 4; ++r) inv[r] = 1.f / l_r[r];
    const int b = bh >> 4, h = bh & 15;
    unsigned short* obase = attb + ((size_t)b*TDIM + q0 + w*16 + g*4)*CDIM + h*DDIM + c;
#pragma unroll
    for (int dt = 0; dt < 8; ++dt)
#pragma unroll
        for (int r = 0; r < 4; ++r)
            obase[(size_t)r*CDIM + dt*16] = f2bf(oacc[dt][r] * inv[r]);
}

extern "C" void kernel_launch(void* const* d_in, const int* in_sizes, int n_in,
                              void* d_out, int out_size, void* d_ws, size_t ws_size,
                              hipStream_t stream)
{
    const float* x    = (const float*)d_in[0];   // [B,T,C]
    const float* Wqkv = (const float*)d_in[1];   // [3C,C]
    const float* Wout = (const float*)d_in[2];   // [C,C]
    float* out = (float*)d_out;

    unsigned short* ws = (unsigned short*)d_ws;
    unsigned short* xb    = ws;                           // 32MB
    unsigned short* Wqkvb = xb    + (size_t)MROWS*CDIM;   // 24MB
    unsigned short* Woutb = Wqkvb + (size_t)NQKV*CDIM;    //  8MB
    unsigned short* Qb    = Woutb + (size_t)CDIM*CDIM;    // [bh,t,d] 32MB
    unsigned short* Kb    = Qb + QSZ;                     // [bh,t,d] 32MB
    unsigned short* Vtb   = Kb + QSZ;                     // [bh,d,t] 32MB
    unsigned short* attb  = Vtb + QSZ;                    // [B,T,C]  32MB

    dim3 blk(256);
    cvt_bf16<<<2048, blk, 0, stream>>>(x,    xb,    MROWS*CDIM/4);
    cvt_bf16<<<2048, blk, 0, stream>>>(Wqkv, Wqkvb, NQKV*CDIM/4);
    cvt_bf16<<<1024, blk, 0, stream>>>(Wout, Woutb, CDIM*CDIM/4);
    gemm_bt<0><<<dim3(MROWS/128, NQKV/128), blk, 0, stream>>>(xb, Wqkvb, nullptr, Qb, Kb, Vtb, NQKV);
    attn_mfma<<<dim3(64*32), blk, 0, stream>>>(Qb, Kb, Vtb, attb);
    gemm_bt<1><<<dim3(MROWS/128, CDIM/128), blk, 0, stream>>>(attb, Woutb, out, nullptr, nullptr, nullptr, CDIM);
}

// Round 6
// 460.148 us; speedup vs baseline: 28.2496x; 1.2270x over previous
//
#include <hip/hip_runtime.h>
#include <hip/hip_bf16.h>
#include <math.h>

#define BDIM 4
#define TDIM 2048
#define CDIM 2048
#define HDIM 16
#define DDIM 128
#define MROWS (BDIM*TDIM)     /* 8192 */
#define NQKV (3*CDIM)         /* 6144 */
#define GK   CDIM             /* 2048 = K of both GEMMs */
#define QSZ  (MROWS*CDIM)

#define NTILES 32             /* GK/64 */
#define NITER  16             /* NTILES/2 */
#define HT     8192           /* bf16 units per [256][32] half-tile */
#define BOFF   32768          /* B region offset in bf16 units (4*HT) */

typedef __attribute__((ext_vector_type(8))) short short8;
typedef __attribute__((ext_vector_type(4))) unsigned short ushort4v;
typedef __attribute__((ext_vector_type(4))) float f32x4;

__device__ __forceinline__ unsigned short f2bf(float f) {
    unsigned int u = __float_as_uint(f);
    u += 0x7fffu + ((u >> 16) & 1u);        // RNE
    return (unsigned short)(u >> 16);
}

__device__ __forceinline__ void gload16(const unsigned short* g, unsigned short* l) {
    __builtin_amdgcn_global_load_lds((__attribute__((address_space(1))) void*)(g),
                                     (__attribute__((address_space(3))) void*)(l),
                                     16, 0, 0);
}

// fp32 -> bf16 bulk convert (memory-bound)
__global__ __launch_bounds__(256) void cvt_bf16(const float* __restrict__ in,
                                                unsigned short* __restrict__ outp,
                                                int n4)
{
    const int stride = gridDim.x * blockDim.x;
    for (int i = blockIdx.x * blockDim.x + threadIdx.x; i < n4; i += stride) {
        float4 f = ((const float4*)in)[i];
        ushort4v u;
        u[0] = f2bf(f.x); u[1] = f2bf(f.y); u[2] = f2bf(f.z); u[3] = f2bf(f.w);
        ((ushort4v*)outp)[i] = u;
    }
}

// ---- 8-phase 256x256 bf16 NT GEMM ----------------------------------------
// Stage one [256][32] half-tile: per wave 2x gload16 (rows w*32+j*16..+16).
// Swizzle: LDS[r][u] = global[r][u ^ ((r>>1)&3)] (16B units); DMA writes
// linearly, so the per-lane GLOBAL source is pre-swizzled (rule #21).
__device__ __forceinline__ void stage_half(const unsigned short* __restrict__ T,
                                           int rowbase, int kcol,
                                           unsigned short* dst, int w, int lane)
{
    const int sw = ((lane & 3) ^ ((lane >> 3) & 3)) * 8;
#pragma unroll
    for (int j = 0; j < 2; ++j) {
        const int r = w*32 + j*16 + (lane >> 2);
        gload16(T + (size_t)(rowbase + r)*GK + kcol + sw, dst + (w*32 + j*16)*32);
    }
}

// One phase: ds-reads -> stage issue -> [vmcnt(4)] -> barrier -> lgkmcnt(0)
// -> setprio(1) 16 MFMA setprio(0) -> barrier.
template<int MQ, int KS, int BUF, bool RDB, bool WAIT>
__device__ __forceinline__ void gphase(unsigned short* lds,
    const unsigned short* __restrict__ stT, int stRow, int stKcol, unsigned short* stDst,
    int wr, int wc, int fr, int colu, int w, int lane,
    short8 (&bfr)[4], f32x4 (&acc)[8][4])
{
    const unsigned short* Ah = lds + (BUF*2 + KS)*HT;
    const unsigned short* Bh = lds + BOFF + (BUF*2 + KS)*HT;
    short8 af[4];
#pragma unroll
    for (int mi = 0; mi < 4; ++mi)
        af[mi] = *(const short8*)&Ah[(wr*128 + (MQ*4 + mi)*16 + fr)*32 + colu];
    if (RDB) {
#pragma unroll
        for (int nj = 0; nj < 4; ++nj)
            bfr[nj] = *(const short8*)&Bh[(wc*64 + nj*16 + fr)*32 + colu];
    }
    stage_half(stT, stRow, stKcol, stDst, w, lane);
    if (WAIT) asm volatile("s_waitcnt vmcnt(4)" ::: "memory");
    __builtin_amdgcn_s_barrier();
    asm volatile("s_waitcnt lgkmcnt(0)" ::: "memory");
    __builtin_amdgcn_sched_barrier(0);
    __builtin_amdgcn_s_setprio(1);
#pragma unroll
    for (int mi = 0; mi < 4; ++mi)
#pragma unroll
        for (int nj = 0; nj < 4; ++nj)
            acc[MQ*4 + mi][nj] = __builtin_amdgcn_mfma_f32_16x16x32_bf16(af[mi], bfr[nj], acc[MQ*4 + mi][nj], 0, 0, 0);
    __builtin_amdgcn_s_setprio(0);
    __builtin_amdgcn_s_barrier();
}

// MODE 0: scatter bf16 to Q/K [bh,t,d] and V TRANSPOSED [bh,d,t].
// MODE 1: fp32 row-major outp.
template<int MODE>
__global__ __launch_bounds__(512, 2) void gemm8(const unsigned short* __restrict__ A,
                                                const unsigned short* __restrict__ B,
                                                float* __restrict__ outp,
                                                unsigned short* __restrict__ qb,
                                                unsigned short* __restrict__ kb,
                                                unsigned short* __restrict__ vt,
                                                int Nsz)
{
    extern __shared__ unsigned short lds[];   // 8*HT bf16 = 128 KB
    const int tid  = threadIdx.x;
    const int w    = tid >> 6;
    const int lane = tid & 63;
    const int wr   = w >> 2, wc = w & 3;
    const int fr   = lane & 15;
    const int fg   = lane >> 4;
    const int colu = (fg ^ ((fr >> 1) & 3)) * 8;
    const int m0   = blockIdx.x * 256, n0 = blockIdx.y * 256;

    f32x4 acc[8][4];
#pragma unroll
    for (int i = 0; i < 8; ++i)
#pragma unroll
        for (int j = 0; j < 4; ++j) acc[i][j] = (f32x4)(0.f);
    short8 bfr[4];

    // prologue: tile0 -> buf0 (all 4 halves), tile1 ks0 -> buf1
    stage_half(A, m0, 0,  lds,             w, lane);   // buf0.A0
    stage_half(B, n0, 0,  lds + BOFF,      w, lane);   // buf0.B0
    stage_half(A, m0, 32, lds + HT,        w, lane);   // buf0.A1
    stage_half(B, n0, 32, lds + BOFF + HT, w, lane);   // buf0.B1
    stage_half(A, m0, 64, lds + 2*HT,        w, lane); // buf1.A0
    stage_half(B, n0, 64, lds + BOFF + 2*HT, w, lane); // buf1.B0
    asm volatile("s_waitcnt vmcnt(0)" ::: "memory");
    __builtin_amdgcn_s_barrier();

    for (int i = 0; i < NITER; ++i) {
        const int t1 = 2*i + 1;
        const int t2 = (2*i + 2 < NTILES) ? 2*i + 2 : 0;   // clamp: dead-buffer garbage
        const int t3 = (2*i + 3 < NTILES) ? 2*i + 3 : 0;
        gphase<0,0,0,true ,false>(lds, A, m0, t1*64+32, lds + 3*HT,        wr, wc, fr, colu, w, lane, bfr, acc); // P1 buf1.A1<-t1
        gphase<1,0,0,false,false>(lds, B, n0, t1*64+32, lds + BOFF + 3*HT, wr, wc, fr, colu, w, lane, bfr, acc); // P2 buf1.B1<-t1
        gphase<0,1,0,true ,false>(lds, A, m0, t2*64,    lds,               wr, wc, fr, colu, w, lane, bfr, acc); // P3 buf0.A0<-t2
        gphase<1,1,0,false,true >(lds, B, n0, t2*64,    lds + BOFF,        wr, wc, fr, colu, w, lane, bfr, acc); // P4 buf0.B0<-t2 +vmcnt
        gphase<0,0,1,true ,false>(lds, A, m0, t2*64+32, lds + HT,          wr, wc, fr, colu, w, lane, bfr, acc); // P5 buf0.A1<-t2
        gphase<1,0,1,false,false>(lds, B, n0, t2*64+32, lds + BOFF + HT,   wr, wc, fr, colu, w, lane, bfr, acc); // P6 buf0.B1<-t2
        gphase<0,1,1,true ,false>(lds, A, m0, t3*64,    lds + 2*HT,        wr, wc, fr, colu, w, lane, bfr, acc); // P7 buf1.A0<-t3
        gphase<1,1,1,false,true >(lds, B, n0, t3*64,    lds + BOFF + 2*HT, wr, wc, fr, colu, w, lane, bfr, acc); // P8 buf1.B0<-t3 +vmcnt
    }
    asm volatile("s_waitcnt vmcnt(0)" ::: "memory");

    if (MODE == 0) {
#pragma unroll
        for (int mi = 0; mi < 8; ++mi)
#pragma unroll
            for (int nj = 0; nj < 4; ++nj) {
                const int n   = n0 + wc*64 + nj*16 + fr;
                const int sel = n >> 11;          // block-uniform
                const int c   = n & 2047;
                const int hh  = c >> 7, dd = c & 127;
                const int mb  = m0 + wr*128 + mi*16 + fg*4;
                const int bb  = mb >> 11, tt = mb & 2047;
                if (sel == 2) {                   // V transposed: [bh][d][t], 4 consec t
                    ushort4v v;
#pragma unroll
                    for (int r = 0; r < 4; ++r) v[r] = f2bf(acc[mi][nj][r]);
                    *(ushort4v*)&vt[((size_t)(bb*HDIM + hh)*DDIM + dd)*TDIM + tt] = v;
                } else {
                    unsigned short* dstb = (sel == 0) ? qb : kb;
#pragma unroll
                    for (int r = 0; r < 4; ++r)
                        dstb[((size_t)(bb*HDIM + hh)*TDIM + tt + r)*DDIM + dd] = f2bf(acc[mi][nj][r]);
                }
            }
    } else {
#pragma unroll
        for (int mi = 0; mi < 8; ++mi)
#pragma unroll
            for (int nj = 0; nj < 4; ++nj) {
                const int n = n0 + wc*64 + nj*16 + fr;
#pragma unroll
                for (int r = 0; r < 4; ++r) {
                    const int m = m0 + wr*128 + mi*16 + fg*4 + r;
                    outp[(size_t)m*Nsz + n] = acc[mi][nj][r];
                }
            }
    }
}

// ---- Flash attention (unchanged from round 5) ----------------------------
__global__ __launch_bounds__(256) void attn_mfma(const unsigned short* __restrict__ Qg,
                                                 const unsigned short* __restrict__ Kg,
                                                 const unsigned short* __restrict__ Vt,
                                                 unsigned short* __restrict__ attb)
{
    __shared__ __align__(16) unsigned short Ks[2][64*128];
    __shared__ __align__(16) unsigned short Vs[128*64];
    __shared__ __align__(16) unsigned short Ps[4*16*64];

    const int tid  = threadIdx.x;
    const int w    = tid >> 6;
    const int lane = tid & 63;
    const int g    = lane >> 4;
    const int c    = lane & 15;
    const int bh   = blockIdx.x & 63;
    const int qt   = 31 - (blockIdx.x >> 6);
    const int q0   = qt * 64;
    const float sc = 0.08838834764831845f;

    const unsigned short* Kbh  = Kg + (size_t)bh*TDIM*DDIM;
    const unsigned short* Vtbh = Vt + (size_t)bh*DDIM*TDIM;

    short8 qf[4];
    {
        const unsigned short* qrow = Qg + ((size_t)bh*TDIM + q0 + w*16 + c)*DDIM + g*8;
#pragma unroll
        for (int s = 0; s < 4; ++s)
            qf[s] = *(const short8*)(qrow + s*32);
    }

    f32x4 oacc[8];
#pragma unroll
    for (int i = 0; i < 8; ++i) oacc[i] = (f32x4)(0.f);
    float m_r[4], l_r[4];
#pragma unroll
    for (int r = 0; r < 4; ++r) { m_r[r] = -INFINITY; l_r[r] = 0.f; }

#define STAGE_K(buf, kt_)                                                        \
    {                                                                            \
        _Pragma("unroll")                                                        \
        for (int j = 0; j < 4; ++j) {                                            \
            const int rw  = w*16 + j*4 + (lane >> 4);                            \
            const int sub = (lane & 15) ^ (rw & 7);                              \
            gload16(Kbh + ((size_t)((kt_)*64 + rw))*DDIM + sub*8,                \
                    &Ks[buf][w*2048 + j*512]);                                   \
        }                                                                        \
    }
#define STAGE_V(kt_)                                                             \
    {                                                                            \
        _Pragma("unroll")                                                        \
        for (int j = 0; j < 4; ++j) {                                            \
            const int d   = w*32 + j*8 + (lane >> 3);                            \
            const int sub = (lane & 7) ^ (d & 7);                                \
            gload16(Vtbh + (size_t)d*TDIM + (kt_)*64 + sub*8,                    \
                    &Vs[w*2048 + j*512]);                                        \
        }                                                                        \
    }

    STAGE_K(0, 0);
    STAGE_V(0);
    __syncthreads();

    for (int kt = 0; kt <= qt; ++kt) {
        const int cur = kt & 1;
        if (kt < qt) STAGE_K(cur ^ 1, kt + 1);
        if (kt > 0)  STAGE_V(kt);

        f32x4 sa[4];
#pragma unroll
        for (int n = 0; n < 4; ++n) sa[n] = (f32x4)(0.f);
#pragma unroll
        for (int s = 0; s < 4; ++s)
#pragma unroll
            for (int n = 0; n < 4; ++n) {
                const int row = n*16 + c;
                short8 bf = *(const short8*)&Ks[cur][(row*128 + s*32 + g*8) ^ ((row&7)<<3)];
                sa[n] = __builtin_amdgcn_mfma_f32_16x16x32_bf16(qf[s], bf, sa[n], 0, 0, 0);
            }

        if (kt == qt) {
#pragma unroll
            for (int n = 0; n < 4; ++n) {
                const int k = n*16 + c;
#pragma unroll
                for (int r = 0; r < 4; ++r) {
                    const int q = w*16 + g*4 + r;
                    if (k > q) sa[n][r] = -INFINITY;
                }
            }
        }

        float corr[4];
#pragma unroll
        for (int r = 0; r < 4; ++r) {
            float mx = fmaxf(fmaxf(sa[0][r], sa[1][r]), fmaxf(sa[2][r], sa[3][r]));
            mx = fmaxf(mx, __shfl_xor(mx, 1));
            mx = fmaxf(mx, __shfl_xor(mx, 2));
            mx = fmaxf(mx, __shfl_xor(mx, 4));
            mx = fmaxf(mx, __shfl_xor(mx, 8));
            const float mn = fmaxf(m_r[r], mx);
            corr[r] = __expf((m_r[r] - mn) * sc);
            float rs = 0.f;
#pragma unroll
            for (int n = 0; n < 4; ++n) {
                const float p = __expf((sa[n][r] - mn) * sc);
                sa[n][r] = p;
                rs += p;
            }
            rs += __shfl_xor(rs, 1);
            rs += __shfl_xor(rs, 2);
            rs += __shfl_xor(rs, 4);
            rs += __shfl_xor(rs, 8);
            l_r[r] = l_r[r]*corr[r] + rs;
            m_r[r] = mn;
        }
#pragma unroll
        for (int i = 0; i < 8; ++i) {
            f32x4 o = oacc[i];
            o[0] *= corr[0]; o[1] *= corr[1]; o[2] *= corr[2]; o[3] *= corr[3];
            oacc[i] = o;
        }

        unsigned short* Pw = &Ps[w*1024];
#pragma unroll
        for (int n = 0; n < 4; ++n)
#pragma unroll
            for (int r = 0; r < 4; ++r) {
                const int q = g*4 + r, k = n*16 + c;
                Pw[(q*64 + k) ^ ((q&7)<<3)] = f2bf(sa[n][r]);
            }
        short8 pf[2];
#pragma unroll
        for (int s2 = 0; s2 < 2; ++s2)
            pf[s2] = *(const short8*)&Pw[(c*64 + s2*32 + g*8) ^ ((c&7)<<3)];

        __syncthreads();

#pragma unroll
        for (int s2 = 0; s2 < 2; ++s2)
#pragma unroll
            for (int dt = 0; dt < 8; ++dt) {
                const int d = dt*16 + c;
                short8 vf = *(const short8*)&Vs[(d*64 + s2*32 + g*8) ^ ((d&7)<<3)];
                oacc[dt] = __builtin_amdgcn_mfma_f32_16x16x32_bf16(pf[s2], vf, oacc[dt], 0, 0, 0);
            }

        __syncthreads();
    }

    float inv[4];
#pragma unroll
    for (int r = 0; r < 4; ++r) inv[r] = 1.f / l_r[r];
    const int b = bh >> 4, h = bh & 15;
    unsigned short* obase = attb + ((size_t)b*TDIM + q0 + w*16 + g*4)*CDIM + h*DDIM + c;
#pragma unroll
    for (int dt = 0; dt < 8; ++dt)
#pragma unroll
        for (int r = 0; r < 4; ++r)
            obase[(size_t)r*CDIM + dt*16] = f2bf(oacc[dt][r] * inv[r]);
}

extern "C" void kernel_launch(void* const* d_in, const int* in_sizes, int n_in,
                              void* d_out, int out_size, void* d_ws, size_t ws_size,
                              hipStream_t stream)
{
    const float* x    = (const float*)d_in[0];   // [B,T,C]
    const float* Wqkv = (const float*)d_in[1];   // [3C,C]
    const float* Wout = (const float*)d_in[2];   // [C,C]
    float* out = (float*)d_out;

    unsigned short* ws = (unsigned short*)d_ws;
    unsigned short* xb    = ws;
    unsigned short* Wqkvb = xb    + (size_t)MROWS*CDIM;
    unsigned short* Woutb = Wqkvb + (size_t)NQKV*CDIM;
    unsigned short* Qb    = Woutb + (size_t)CDIM*CDIM;    // [bh,t,d]
    unsigned short* Kb    = Qb + QSZ;                     // [bh,t,d]
    unsigned short* Vtb   = Kb + QSZ;                     // [bh,d,t]
    unsigned short* attb  = Vtb + QSZ;                    // [B,T,C]

    cvt_bf16<<<2048, 256, 0, stream>>>(x,    xb,    MROWS*CDIM/4);
    cvt_bf16<<<2048, 256, 0, stream>>>(Wqkv, Wqkvb, NQKV*CDIM/4);
    cvt_bf16<<<1024, 256, 0, stream>>>(Wout, Woutb, CDIM*CDIM/4);
    gemm8<0><<<dim3(MROWS/256, NQKV/256), 512, 131072, stream>>>(xb, Wqkvb, nullptr, Qb, Kb, Vtb, NQKV);
    attn_mfma<<<dim3(64*32), 256, 0, stream>>>(Qb, Kb, Vtb, attb);
    gemm8<1><<<dim3(MROWS/256, CDIM/256), 512, 131072, stream>>>(attb, Woutb, out, nullptr, nullptr, nullptr, CDIM);
}